// Round 1
// baseline (1189.143 us; speedup 1.0000x reference)
//
#include <hip/hip_runtime.h>
#include <math.h>

#define DIM 4096
#define HIDDEN 11008
#define NB 32          // batch
#define EPS 1e-5f

// ---------------- RMSNorm, writes transposed (K x 32) ----------------
__global__ __launch_bounds__(256) void rmsnorm_t_kernel(
    const float* __restrict__ x, const float* __restrict__ w,
    float* __restrict__ outT)
{
  int m = blockIdx.x;           // 0..31
  int tid = threadIdx.x;
  const float4* xr = (const float4*)(x + (size_t)m * DIM);
  const float4* wr = (const float4*)w;
  float4 xv[4];
  float s = 0.f;
#pragma unroll
  for (int i = 0; i < 4; i++) {
    xv[i] = xr[tid + i * 256];
    s += xv[i].x * xv[i].x + xv[i].y * xv[i].y + xv[i].z * xv[i].z + xv[i].w * xv[i].w;
  }
#pragma unroll
  for (int off = 32; off > 0; off >>= 1) s += __shfl_down(s, off, 64);
  __shared__ float wsum[4];
  if ((tid & 63) == 0) wsum[tid >> 6] = s;
  __syncthreads();
  float tot = wsum[0] + wsum[1] + wsum[2] + wsum[3];
  float scale = 1.0f / (sqrtf(tot / (float)DIM) + EPS);
#pragma unroll
  for (int i = 0; i < 4; i++) {
    float4 wv = wr[tid + i * 256];
    int k = (tid + i * 256) * 4;
    outT[(size_t)(k + 0) * NB + m] = xv[i].x * wv.x * scale;
    outT[(size_t)(k + 1) * NB + m] = xv[i].y * wv.y * scale;
    outT[(size_t)(k + 2) * NB + m] = xv[i].z * wv.z * scale;
    outT[(size_t)(k + 3) * NB + m] = xv[i].w * wv.w * scale;
  }
}

// ---------------- skinny GEMM: C(32 x ldc) += AT(K x 32)^T * W(K x ldw) ----------------
// grid.x = columns/64, grid.y = K splits; split-K combined via fp32 atomicAdd.
__global__ __launch_bounds__(256) void gemm32_kernel(
    const float* __restrict__ AT,   // K x 32
    const float* __restrict__ W,    // K x ldw, row-major
    float* __restrict__ C,          // 32 x ldc, pre-initialized (residue or zero)
    int ldw, int ldc, int colOff, int K, int kPerBlk)
{
  __shared__ float Wl[64 * 64];     // 16 KB
  __shared__ float Al[64 * 32];     // 8 KB
  int tid = threadIdx.x;
  int tn = tid & 63, tm = tid >> 6;
  int colBase = blockIdx.x * 64;
  int k0 = blockIdx.y * kPerBlk;
  int kEnd = k0 + kPerBlk; if (kEnd > K) kEnd = K;
  float acc[8] = {0.f, 0.f, 0.f, 0.f, 0.f, 0.f, 0.f, 0.f};

  for (int kt = k0; kt < kEnd; kt += 64) {
    int tk = kEnd - kt; if (tk > 64) tk = 64;
    __syncthreads();
#pragma unroll
    for (int i = 0; i < 4; i++) {
      int e = tid + i * 256;                // 1024 float4-groups: 64 rows x 16
      int row = e >> 4, c = (e & 15) << 2;
      float4 v = make_float4(0.f, 0.f, 0.f, 0.f);
      if (row < tk) v = *(const float4*)&W[(size_t)(kt + row) * ldw + colBase + c];
      *(float4*)&Wl[row * 64 + c] = v;
    }
#pragma unroll
    for (int i = 0; i < 2; i++) {
      int e = tid + i * 256;                // 512 groups: 64 rows x 8
      int row = e >> 3, c = (e & 7) << 2;
      float4 v = make_float4(0.f, 0.f, 0.f, 0.f);
      if (row < tk) v = *(const float4*)&AT[(size_t)(kt + row) * NB + c];
      *(float4*)&Al[row * NB + c] = v;
    }
    __syncthreads();
#pragma unroll 4
    for (int kk = 0; kk < tk; kk++) {
      float wv = Wl[kk * 64 + tn];
      float4 a0 = *(const float4*)&Al[kk * NB + tm * 8];
      float4 a1 = *(const float4*)&Al[kk * NB + tm * 8 + 4];
      acc[0] += a0.x * wv; acc[1] += a0.y * wv; acc[2] += a0.z * wv; acc[3] += a0.w * wv;
      acc[4] += a1.x * wv; acc[5] += a1.y * wv; acc[6] += a1.z * wv; acc[7] += a1.w * wv;
    }
  }
  float* cb = C + (size_t)(tm * 8) * ldc + colOff + colBase + tn;
#pragma unroll
  for (int i = 0; i < 8; i++) atomicAdd(cb + (size_t)i * ldc, acc[i]);
}

// ---------------- RoPE in place on q (32 heads) and k (8 heads) ----------------
__global__ __launch_bounds__(256) void rope_kernel(
    float* __restrict__ qkv, const float* __restrict__ cosv, const float* __restrict__ sinv)
{
  int idx = blockIdx.x * 256 + threadIdx.x;   // 32 * 40 * 64
  int j = idx & 63;
  int h = (idx >> 6) % 40;
  int b = idx / (64 * 40);
  int col = (h < 32) ? (h * 128 + 2 * j) : (DIM + (h - 32) * 128 + 2 * j);
  float* p = qkv + (size_t)b * 6144 + col;
  float c = cosv[j], s = sinv[j];
  float x0 = p[0], x1 = p[1];
  p[0] = x0 * c - x1 * s;
  p[1] = x0 * s + x1 * c;
}

// ---------------- attention: one block per (b, kv-head g); L = 1025 ----------------
__global__ __launch_bounds__(256) void attn_kernel(
    const float* __restrict__ qkv,
    const float* __restrict__ ck, const float* __restrict__ cv,
    float* __restrict__ attnoT)
{
  __shared__ float qs[4 * 128];       // 2 KB
  __shared__ float sc[4 * 1026];      // 16.4 KB (padded row stride)
  __shared__ float kvt[64 * 129];     // 33 KB, pad 129 -> conflict-free
  __shared__ float invs[4];
  int tid = threadIdx.x;
  int b = blockIdx.x >> 3, g = blockIdx.x & 7;
  const float scale = 0.08838834764831845f;   // 1/sqrt(128)

  // load q for heads g*4 .. g*4+3 (contiguous 512 cols starting at g*512)
  for (int i = tid; i < 512; i += 256)
    qs[i] = qkv[(size_t)b * 6144 + (size_t)g * 512 + i];

  const float* kbase = ck + (((size_t)b * 2048) * 8 + g) * 128;   // row stride 1024 floats
  float4 pre[8];

  // prologue: tile 0 of K
#pragma unroll
  for (int i = 0; i < 8; i++) {
    int e = tid + i * 256;
    int row = e >> 5, c = (e & 31) << 2;
    pre[i] = *(const float4*)&kbase[(size_t)row * 1024 + c];
  }
#pragma unroll
  for (int i = 0; i < 8; i++) {
    int e = tid + i * 256;
    int row = e >> 5, c = (e & 31) << 2;
    float* d = &kvt[row * 129 + c];
    d[0] = pre[i].x; d[1] = pre[i].y; d[2] = pre[i].z; d[3] = pre[i].w;
  }
  __syncthreads();

  int r1 = tid >> 6, l1 = tid & 63;
  for (int t = 0; t < 16; t++) {
    if (t < 15) {                       // prefetch next tile into registers
      int l0 = (t + 1) * 64;
#pragma unroll
      for (int i = 0; i < 8; i++) {
        int e = tid + i * 256;
        int row = e >> 5, c = (e & 31) << 2;
        pre[i] = *(const float4*)&kbase[(size_t)(l0 + row) * 1024 + c];
      }
    }
    float a = 0.f;
    const float* kr = &kvt[l1 * 129];
    const float* qr = &qs[r1 * 128];
#pragma unroll 8
    for (int d = 0; d < 128; d++) a += qr[d] * kr[d];
    sc[r1 * 1026 + t * 64 + l1] = a * scale;
    __syncthreads();
    if (t < 15) {
#pragma unroll
      for (int i = 0; i < 8; i++) {
        int e = tid + i * 256;
        int row = e >> 5, c = (e & 31) << 2;
        float* d = &kvt[row * 129 + c];
        d[0] = pre[i].x; d[1] = pre[i].y; d[2] = pre[i].z; d[3] = pre[i].w;
      }
      __syncthreads();
    }
  }

  // tail score: l = 1024 uses fresh roped k from qkv
  {
    const float* kn = qkv + (size_t)b * 6144 + DIM + (size_t)g * 128;
    float part = qs[r1 * 128 + l1] * kn[l1] + qs[r1 * 128 + 64 + l1] * kn[64 + l1];
#pragma unroll
    for (int off = 32; off > 0; off >>= 1) part += __shfl_down(part, off, 64);
    if (l1 == 0) sc[r1 * 1026 + 1024] = part * scale;
  }
  __syncthreads();

  // softmax: wave r1 owns row r1
  {
    float m = -1e30f;
    for (int l = l1; l < 1025; l += 64) m = fmaxf(m, sc[r1 * 1026 + l]);
#pragma unroll
    for (int off = 32; off > 0; off >>= 1) m = fmaxf(m, __shfl_xor(m, off, 64));
    float ssum = 0.f;
    for (int l = l1; l < 1025; l += 64) {
      float e = __expf(sc[r1 * 1026 + l] - m);
      sc[r1 * 1026 + l] = e;
      ssum += e;
    }
#pragma unroll
    for (int off = 32; off > 0; off >>= 1) ssum += __shfl_xor(ssum, off, 64);
    if (l1 == 0) invs[r1] = 1.0f / ssum;
  }
  __syncthreads();

  // V phase
  const float* vbase = cv + (((size_t)b * 2048) * 8 + g) * 128;
#pragma unroll
  for (int i = 0; i < 8; i++) {
    int e = tid + i * 256;
    int row = e >> 5, c = (e & 31) << 2;
    pre[i] = *(const float4*)&vbase[(size_t)row * 1024 + c];
  }
#pragma unroll
  for (int i = 0; i < 8; i++) {
    int e = tid + i * 256;
    int row = e >> 5, c = (e & 31) << 2;
    float* d = &kvt[row * 129 + c];
    d[0] = pre[i].x; d[1] = pre[i].y; d[2] = pre[i].z; d[3] = pre[i].w;
  }
  __syncthreads();

  int dd = tid & 127, rr = tid >> 7;      // rows rr and rr+2
  float a0 = 0.f, a1 = 0.f;
  for (int t = 0; t < 16; t++) {
    if (t < 15) {
      int l0 = (t + 1) * 64;
#pragma unroll
      for (int i = 0; i < 8; i++) {
        int e = tid + i * 256;
        int row = e >> 5, c = (e & 31) << 2;
        pre[i] = *(const float4*)&vbase[(size_t)(l0 + row) * 1024 + c];
      }
    }
    const float* p0 = &sc[rr * 1026 + t * 64];
    const float* p1 = &sc[(rr + 2) * 1026 + t * 64];
#pragma unroll 8
    for (int l = 0; l < 64; l++) {
      float v = kvt[l * 129 + dd];
      a0 += p0[l] * v;
      a1 += p1[l] * v;
    }
    __syncthreads();
    if (t < 15) {
#pragma unroll
      for (int i = 0; i < 8; i++) {
        int e = tid + i * 256;
        int row = e >> 5, c = (e & 31) << 2;
        float* d = &kvt[row * 129 + c];
        d[0] = pre[i].x; d[1] = pre[i].y; d[2] = pre[i].z; d[3] = pre[i].w;
      }
      __syncthreads();
    }
  }
  // tail l = 1024: fresh v from qkv
  {
    const float* vn = qkv + (size_t)b * 6144 + DIM + 1024 + (size_t)g * 128;
    float v = vn[dd];
    a0 += sc[rr * 1026 + 1024] * v;
    a1 += sc[(rr + 2) * 1026 + 1024] * v;
  }
  float i0 = invs[rr], i1 = invs[rr + 2];
  attnoT[(size_t)((g * 4 + rr) * 128 + dd) * NB + b] = a0 * i0;
  attnoT[(size_t)((g * 4 + rr + 2) * 128 + dd) * NB + b] = a1 * i1;
}

// ---------------- SwiGLU elementwise, writes transposed (HIDDEN x 32) ----------------
__global__ __launch_bounds__(256) void silu_kernel(
    const float* __restrict__ gu, float* __restrict__ actT)
{
  int idx = blockIdx.x * 256 + threadIdx.x;   // 11008*32, idx = j*32+m
  int j = idx >> 5, m = idx & 31;
  float g = gu[(size_t)m * 22016 + j];
  float u = gu[(size_t)m * 22016 + HIDDEN + j];
  float sg = g / (1.0f + __expf(-g));
  actT[idx] = sg * u;
}

// ---------------- float4 copy ----------------
__global__ __launch_bounds__(256) void copy4_kernel(
    float* __restrict__ dst, const float* __restrict__ src)
{
  int idx = blockIdx.x * 256 + threadIdx.x;
  ((float4*)dst)[idx] = ((const float4*)src)[idx];
}

extern "C" void kernel_launch(void* const* d_in, const int* in_sizes, int n_in,
                              void* d_out, int out_size, void* d_ws, size_t ws_size,
                              hipStream_t stream)
{
  const float* x   = (const float*)d_in[0];
  // d_in[1] = start_pos (always 1024, compile-time constant here)
  const float* fc  = (const float*)d_in[2];
  const float* fs  = (const float*)d_in[3];
  const float* ck  = (const float*)d_in[4];
  const float* cv  = (const float*)d_in[5];
  const float* wq  = (const float*)d_in[6];
  const float* wk  = (const float*)d_in[7];
  const float* wv  = (const float*)d_in[8];
  const float* wo  = (const float*)d_in[9];
  const float* w1  = (const float*)d_in[10];
  const float* w2  = (const float*)d_in[11];
  const float* w3  = (const float*)d_in[12];
  const float* anw = (const float*)d_in[13];
  const float* fnw = (const float*)d_in[14];
  float* out = (float*)d_out;

  float* ws     = (float*)d_ws;
  float* qkv    = ws;                  // 32 x 6144          (196608)
  float* gateup = ws + 196608;         // 32 x 22016         (704512)
  float* hT     = ws + 901120;         // 4096 x 32          (131072)
  float* out1   = ws + 1032192;        // 32 x 4096          (131072)
  float* h2T    = ws + 1163264;        // 4096 x 32          (131072)
  float* actT   = ws + 1294336;        // 11008 x 32         (352256)
  float* attnoT = ws + 1646592;        // 4096 x 32          (131072)

  // zero the atomic-accumulated buffers (qkv + gateup are adjacent)
  hipMemsetAsync(qkv, 0, (size_t)(196608 + 704512) * sizeof(float), stream);

  // h = rmsnorm(x) -> transposed
  rmsnorm_t_kernel<<<32, 256, 0, stream>>>(x, anw, hT);

  // q/k/v projections
  gemm32_kernel<<<dim3(64, 8),  256, 0, stream>>>(hT, wq, qkv, 4096, 6144, 0,    4096, 512);
  gemm32_kernel<<<dim3(16, 32), 256, 0, stream>>>(hT, wk, qkv, 1024, 6144, 4096, 4096, 128);
  gemm32_kernel<<<dim3(16, 32), 256, 0, stream>>>(hT, wv, qkv, 1024, 6144, 5120, 4096, 128);

  // rope on q,k (position 1024)
  rope_kernel<<<320, 256, 0, stream>>>(qkv, fc, fs);

  // attention over 1024 cached + 1 fresh position
  attn_kernel<<<256, 256, 0, stream>>>(qkv, ck, cv, attnoT);

  // out1 = x + attn_out @ wo
  copy4_kernel<<<128, 256, 0, stream>>>(out1, x);
  gemm32_kernel<<<dim3(64, 8), 256, 0, stream>>>(attnoT, wo, out1, 4096, 4096, 0, 4096, 512);

  // h2 = rmsnorm(out1)
  rmsnorm_t_kernel<<<32, 256, 0, stream>>>(out1, fnw, h2T);

  // gate/up projections
  gemm32_kernel<<<dim3(172, 4), 256, 0, stream>>>(h2T, w1, gateup, HIDDEN, 22016, 0,      4096, 1024);
  gemm32_kernel<<<dim3(172, 4), 256, 0, stream>>>(h2T, w3, gateup, HIDDEN, 22016, HIDDEN, 4096, 1024);

  // act = silu(gate) * up  -> transposed
  silu_kernel<<<1376, 256, 0, stream>>>(gateup, actT);

  // out = out1 + act @ w2
  copy4_kernel<<<128, 256, 0, stream>>>(out, out1);
  gemm32_kernel<<<dim3(64, 16), 256, 0, stream>>>(actT, w2, out, 4096, 4096, 0, HIDDEN, 688);
}